// Round 7
// baseline (324.994 us; speedup 1.0000x reference)
//
#include <hip/hip_runtime.h>
#include <stdint.h>

#define BB 512
#define TT 1000
#define CC 64
#define HH 128
#define TDA_F 150
#define NCLS 4
#define EPSV 1e-5f
#define NSEG 8
#define SEGLEN 125   // TT / NSEG
#define WARM 51      // uncounted warm-up; SEGLEN+WARM = 176 = 11 tiles of 16
#define CPAD 20      // cur row stride (floats): b128 ops land at data-minimum banks

typedef _Float16 half8 __attribute__((ext_vector_type(8)));
typedef float floatx4 __attribute__((ext_vector_type(4)));

__device__ __forceinline__ half8 cvt8(const float4& a, const float4& b) {
  half8 r;
  r[0] = (_Float16)a.x; r[1] = (_Float16)a.y;
  r[2] = (_Float16)a.z; r[3] = (_Float16)a.w;
  r[4] = (_Float16)b.x; r[5] = (_Float16)b.y;
  r[6] = (_Float16)b.z; r[7] = (_Float16)b.w;
  return r;
}

// ---------------------------------------------------------------------------
// Fused current-GEMM (fp16 MFMA) + LIF scan. Grid: 512 b x 8 seg, one wave
// per block. REGISTER BUDGET IS THE DESIGN CONSTRAINT (R2/R6 both died on
// spills): B frags plain fp16 (16 half8 = 64 regs, not hi/lo 128), C-frags
// written to LDS immediately (no acc[8] batch), scan reads pairwise (8 live
// regs). Total ~156 < 170 => __launch_bounds__(64,3): 12 waves/CU.
// Per 16-step tile: currents[16t x 128h] = kin_tile @ Wfc^T + b via 16x
// mfma_f32_16x16x32_f16; C through cur[h][t] (CPAD 20, h-major) with one
// ds_write_b128 per ht; same-iteration scan reads b128 pairs (single-wave
// DS program-order makes the cross-lane transpose barrier-free); LIF 2
// h/lane. 2-deep register prefetch of A covers HBM latency.
// fp16 A+B rounding: current err ~1e-3 worst -> rare +-1 spike flips on top
// of warm-up's absmax 3 (R5/R6 measured); output-1 threshold is 19.28.
// ---------------------------------------------------------------------------
__global__ __launch_bounds__(64, 3) void snn_scan(
    const float* __restrict__ kin, const float* __restrict__ Wfc,
    const float* __restrict__ bfc, float* __restrict__ part)
{
  const int lane = threadIdx.x;
  const int q = lane >> 4;      // quad 0..3
  const int ml = lane & 15;     // m (=t row) for A / n (=h col) for B
  const int b = blockIdx.x >> 3;
  const int seg = blockIdx.x & 7;

  const int t0 = (seg == 0) ? 0 : SEGLEN * seg - WARM;
  const int ntiles = (seg == 0) ? 8 : 11;   // 128 or 176 steps
  const int lo = SEGLEN * seg;
  const int hi = lo + SEGLEN;

  // B fragments: W[n=ht*16+ml][k=kh*32+q*8+j] as plain fp16. 64 VGPRs.
  half8 bfrag[8][2];
  float bv[8];
#pragma unroll
  for (int ht = 0; ht < 8; ++ht) {
    bv[ht] = bfc[ht * 16 + ml];
#pragma unroll
    for (int kh = 0; kh < 2; ++kh) {
      const float* wp = Wfc + (ht * 16 + ml) * CC + kh * 32 + q * 8;
      float4 w0 = *(const float4*)(wp);
      float4 w1 = *(const float4*)(wp + 4);
      bfrag[ht][kh] = cvt8(w0, w1);
    }
  }

  __shared__ float cur[HH * CPAD];  // 10,240 B

  // A loads: lane covers row t = t0 + tile*16 + ml, k-cols q*8 (+0 / +32).
  const float* ab = kin + ((size_t)b * TT + (t0 + ml)) * CC + q * 8;

  float4 p[2][4];
#pragma unroll
  for (int i = 0; i < 2; ++i) {
    const float* s = ab + i * 16 * CC;
    p[i][0] = *(const float4*)(s);
    p[i][1] = *(const float4*)(s + 4);
    p[i][2] = *(const float4*)(s + 32);
    p[i][3] = *(const float4*)(s + 36);
  }

  float mem0 = 0.f, mem1 = 0.f, cnt0 = 0.f, cnt1 = 0.f;

  for (int c = 0; c < ntiles; ++c) {
    half8 a0 = cvt8(p[c & 1][0], p[c & 1][1]);
    half8 a1 = cvt8(p[c & 1][2], p[c & 1][3]);

    // Prefetch tile c+2 into the slot just freed.
    if (c + 2 < ntiles) {
      const float* s = ab + (size_t)(c + 2) * 16 * CC;
      p[c & 1][0] = *(const float4*)(s);
      p[c & 1][1] = *(const float4*)(s + 4);
      p[c & 1][2] = *(const float4*)(s + 32);
      p[c & 1][3] = *(const float4*)(s + 36);
    }

    // MFMA tile c, write each ht's C-frag immediately:
    // D[row=t=q*4+r][col=h=ht*16+ml] -> cur[h][t], r contiguous => b128.
#pragma unroll
    for (int ht = 0; ht < 8; ++ht) {
      floatx4 a = {bv[ht], bv[ht], bv[ht], bv[ht]};  // bias folded in
      a = __builtin_amdgcn_mfma_f32_16x16x32_f16(a0, bfrag[ht][0], a, 0, 0, 0);
      a = __builtin_amdgcn_mfma_f32_16x16x32_f16(a1, bfrag[ht][1], a, 0, 0, 0);
      float4 st = {a[0], a[1], a[2], a[3]};
      *(float4*)(cur + (ht * 16 + ml) * CPAD + q * 4) = st;
    }

    // Scan tile c. Single-wave DS ops execute in program order, so these
    // reads see the writes above without a barrier. Pairwise reads keep
    // only 8 scan floats live.
    const float4* r0 = (const float4*)(cur + lane * CPAD);
    const float4* r1 = (const float4*)(cur + (lane + 64) * CPAD);
    const int tb = t0 + c * 16;
#pragma unroll
    for (int i = 0; i < 4; ++i) {
      float4 v0 = r0[i];
      float4 v1 = r1[i];
#pragma unroll
      for (int k = 0; k < 4; ++k) {
        const int t = tb + i * 4 + k;
        const bool act = (t >= lo) && (t < hi);  // wave-uniform
        const float f0 = (k == 0) ? v0.x : (k == 1) ? v0.y : (k == 2) ? v0.z : v0.w;
        const float f1 = (k == 0) ? v1.x : (k == 1) ? v1.y : (k == 2) ? v1.z : v1.w;
        mem0 = fmaf(0.9f, mem0, f0);
        mem1 = fmaf(0.9f, mem1, f1);
        const bool s0 = (mem0 >= 1.0f);
        const bool s1 = (mem1 >= 1.0f);
        cnt0 += (act && s0) ? 1.0f : 0.0f;
        cnt1 += (act && s1) ? 1.0f : 0.0f;
        mem0 = s0 ? 0.0f : mem0;
        mem1 = s1 ? 0.0f : mem1;
      }
    }
  }

  float* pp = part + ((size_t)(seg * BB + b)) * HH;
  pp[lane] = cnt0;
  pp[lane + 64] = cnt1;
}

// ---------------------------------------------------------------------------
// Fused head: partial-count reduce + counts output + tda_net
// (150->64 relu ->64 relu) + fc1 (192->128). No atomics.
// ---------------------------------------------------------------------------
__global__ __launch_bounds__(HH) void fused_head(
    const float* __restrict__ part, const float* __restrict__ tda,
    const float* __restrict__ W1, const float* __restrict__ b1,
    const float* __restrict__ W2, const float* __restrict__ b2,
    const float* __restrict__ Wc1, const float* __restrict__ bc1,
    float* __restrict__ counts_out, float* __restrict__ hbuf)
{
  const int b = blockIdx.x, j = threadIdx.x;
  __shared__ float x[TDA_F];
  __shared__ float h1[64];
  __shared__ float f[HH + 64];

  float c = 0.0f;
#pragma unroll
  for (int s = 0; s < NSEG; ++s) c += part[((size_t)(s * BB + b)) * HH + j];
  counts_out[b * HH + j] = c;
  f[j] = c * (1.0f / TT);
  for (int i = j; i < TDA_F; i += HH) x[i] = tda[b * TDA_F + i];
  __syncthreads();
  if (j < 64) {
    float acc = b1[j];
    const float* wr = W1 + j * TDA_F;
#pragma unroll 5
    for (int i = 0; i < TDA_F; ++i) acc = fmaf(x[i], wr[i], acc);
    h1[j] = fmaxf(acc, 0.0f);
  }
  __syncthreads();
  if (j < 64) {
    float acc = b2[j];
    const float* wr = W2 + j * 64;
#pragma unroll
    for (int i = 0; i < 64; ++i) acc = fmaf(h1[i], wr[i], acc);
    f[HH + j] = fmaxf(acc, 0.0f);
  }
  __syncthreads();
  float acc = bc1[j];
  const float* wr = Wc1 + j * (HH + 64);
#pragma unroll 4
  for (int i = 0; i < HH + 64; ++i) acc = fmaf(f[i], wr[i], acc);
  hbuf[b * HH + j] = acc;
}

// ---------------------------------------------------------------------------
// BN (batch stats computed per-block from L2-resident hbuf) + relu +
// 128->4 GEMM.
// ---------------------------------------------------------------------------
__global__ __launch_bounds__(HH) void classifier2(
    const float* __restrict__ hbuf,
    const float* __restrict__ gamma, const float* __restrict__ beta,
    const float* __restrict__ Wc2, const float* __restrict__ bc2,
    float* __restrict__ out)
{
  const int b = blockIdx.x, j = threadIdx.x;
  float s0 = 0.f, q0 = 0.f, s1 = 0.f, q1 = 0.f;
  for (int r = 0; r < BB; r += 2) {
    float v0 = hbuf[r * HH + j];
    float v1 = hbuf[(r + 1) * HH + j];
    s0 += v0; q0 = fmaf(v0, v0, q0);
    s1 += v1; q1 = fmaf(v1, v1, q1);
  }
  const float mean = (s0 + s1) * (1.0f / BB);
  const float var = (q0 + q1) * (1.0f / BB) - mean * mean;
  const float rstd = rsqrtf(var + EPSV);

  float hn = (hbuf[b * HH + j] - mean) * rstd * gamma[j] + beta[j];
  hn = fmaxf(hn, 0.0f);

  __shared__ float red[NCLS][HH];
#pragma unroll
  for (int k = 0; k < NCLS; ++k) red[k][j] = hn * Wc2[k * HH + j];
  __syncthreads();
  for (int off = HH / 2; off >= 1; off >>= 1) {
    if (j < off) {
#pragma unroll
      for (int k = 0; k < NCLS; ++k) red[k][j] += red[k][j + off];
    }
    __syncthreads();
  }
  if (j < NCLS) out[b * NCLS + j] = red[j][0] + bc2[j];
}

// ---------------------------------------------------------------------------
extern "C" void kernel_launch(void* const* d_in, const int* in_sizes, int n_in,
                              void* d_out, int out_size, void* d_ws, size_t ws_size,
                              hipStream_t stream)
{
  const float* kin  = (const float*)d_in[0];   // [512,1000,64]
  const float* tda  = (const float*)d_in[1];   // [512,150]
  const float* Wfc  = (const float*)d_in[2];   // [128,64]
  const float* bfc  = (const float*)d_in[3];   // [128]
  const float* Wt1  = (const float*)d_in[4];   // [64,150]
  const float* bt1  = (const float*)d_in[5];   // [64]
  const float* Wt2  = (const float*)d_in[6];   // [64,64]
  const float* bt2  = (const float*)d_in[7];   // [64]
  const float* Wc1  = (const float*)d_in[8];   // [128,192]
  const float* bc1  = (const float*)d_in[9];   // [128]
  const float* gam  = (const float*)d_in[10];  // [128]
  const float* bet  = (const float*)d_in[11];  // [128]
  const float* Wc2  = (const float*)d_in[12];  // [4,128]
  const float* bc2  = (const float*)d_in[13];  // [4]

  float* out    = (float*)d_out;        // output 0: [512,4]
  float* counts = out + BB * NCLS;      // output 1: [512,128]

  float* part = (float*)d_ws;               // [8][512][128]  (2 MB)
  float* hbuf = part + NSEG * BB * HH;      // [512,128]

  snn_scan<<<BB * NSEG, 64, 0, stream>>>(kin, Wfc, bfc, part);
  fused_head<<<BB, HH, 0, stream>>>(part, tda, Wt1, bt1, Wt2, bt2,
                                    Wc1, bc1, counts, hbuf);
  classifier2<<<BB, HH, 0, stream>>>(hbuf, gam, bet, Wc2, bc2, out);
}

// Round 8
// 313.153 us; speedup vs baseline: 1.0378x; 1.0378x over previous
//
#include <hip/hip_runtime.h>
#include <stdint.h>

#define BB 512
#define TT 1000
#define CC 64
#define HH 128
#define TDA_F 150
#define NCLS 4
#define EPSV 1e-5f
#define NSEG 8
#define SEGLEN 125   // TT / NSEG
#define WARM 51      // uncounted warm-up; SEGLEN+WARM = 176 = 11 tiles of 16
#define CPAD 20      // cur row stride (floats)

typedef _Float16 half8 __attribute__((ext_vector_type(8)));
typedef float floatx4 __attribute__((ext_vector_type(4)));

__device__ __forceinline__ half8 cvt8(const float4& a, const float4& b) {
  half8 r;
  r[0] = (_Float16)a.x; r[1] = (_Float16)a.y;
  r[2] = (_Float16)a.z; r[3] = (_Float16)a.w;
  r[4] = (_Float16)b.x; r[5] = (_Float16)b.y;
  r[6] = (_Float16)b.z; r[7] = (_Float16)b.w;
  return r;
}

// ---------------------------------------------------------------------------
// Fused current-GEMM (fp16 MFMA) + LIF scan. Grid: 512 b x 8 seg, one wave
// per block, __launch_bounds__(64,2) -- THE ONLY PROVEN-CLEAN CONFIG.
// Spill post-mortems: R2 (64,3)=170-cap spill; R6 (64,2) peak-live ~230
// (B hi/lo 128 + acc 32 + scan 32 + p 32) spill; R7 (64,3)=128-cap split
// 64 VGPR + 64 AGPR spill. WRITE_SIZE is the spill canary (2 MB = clean).
// This round: R5's proven per-tile order (MFMA -> scan c-1 -> write) with
// plain-fp16 B (64 regs; fp16-B numerics validated R7, absmax 4.0), b128
// LDS both directions (16 LDS inst/tile vs R5's 64 scalar), pairwise scan
// reads (8 floats live, never 32 next to acc[8]).
// Peak live ~168 << 256. 2-deep A prefetch covers ~900cyc HBM latency.
// Segments s>=1: WARM uncounted steps (LIF reset coalescence; thr 19.28).
// ---------------------------------------------------------------------------
__global__ __launch_bounds__(64, 2) void snn_scan(
    const float* __restrict__ kin, const float* __restrict__ Wfc,
    const float* __restrict__ bfc, float* __restrict__ part)
{
  const int lane = threadIdx.x;
  const int q = lane >> 4;      // quad 0..3
  const int ml = lane & 15;     // m (=t row) for A / n (=h col) for B
  const int b = blockIdx.x >> 3;
  const int seg = blockIdx.x & 7;

  const int t0 = (seg == 0) ? 0 : SEGLEN * seg - WARM;
  const int ntiles = (seg == 0) ? 8 : 11;   // 128 or 176 steps
  const int lo = SEGLEN * seg;
  const int hi = lo + SEGLEN;

  // B fragments: W[n=ht*16+ml][k=kh*32+q*8+j] as plain fp16. 64 regs.
  half8 bfrag[8][2];
  float bv[8];
#pragma unroll
  for (int ht = 0; ht < 8; ++ht) {
    bv[ht] = bfc[ht * 16 + ml];
#pragma unroll
    for (int kh = 0; kh < 2; ++kh) {
      const float* wp = Wfc + (ht * 16 + ml) * CC + kh * 32 + q * 8;
      float4 w0 = *(const float4*)(wp);
      float4 w1 = *(const float4*)(wp + 4);
      bfrag[ht][kh] = cvt8(w0, w1);
    }
  }

  __shared__ float cur[HH * CPAD];  // 10,240 B

  // A loads: lane covers row t = t0 + tile*16 + ml, k-cols q*8 (+0 / +32).
  const float* ab = kin + ((size_t)b * TT + (t0 + ml)) * CC + q * 8;

  float4 p[2][4];
#pragma unroll
  for (int i = 0; i < 2; ++i) {
    const float* s = ab + i * 16 * CC;
    p[i][0] = *(const float4*)(s);
    p[i][1] = *(const float4*)(s + 4);
    p[i][2] = *(const float4*)(s + 32);
    p[i][3] = *(const float4*)(s + 36);
  }

  float mem0 = 0.f, mem1 = 0.f, cnt0 = 0.f, cnt1 = 0.f;

  for (int c = 0; c < ntiles; ++c) {
    half8 a0 = cvt8(p[c & 1][0], p[c & 1][1]);
    half8 a1 = cvt8(p[c & 1][2], p[c & 1][3]);

    // Prefetch tile c+2 into the slot just freed.
    if (c + 2 < ntiles) {
      const float* s = ab + (size_t)(c + 2) * 16 * CC;
      p[c & 1][0] = *(const float4*)(s);
      p[c & 1][1] = *(const float4*)(s + 4);
      p[c & 1][2] = *(const float4*)(s + 32);
      p[c & 1][3] = *(const float4*)(s + 36);
    }

    // MFMA tile c: 8 h-tiles x 2 k-halves, bias folded into acc init.
    floatx4 acc[8];
#pragma unroll
    for (int ht = 0; ht < 8; ++ht) {
      floatx4 a = {bv[ht], bv[ht], bv[ht], bv[ht]};
      a = __builtin_amdgcn_mfma_f32_16x16x32_f16(a0, bfrag[ht][0], a, 0, 0, 0);
      a = __builtin_amdgcn_mfma_f32_16x16x32_f16(a1, bfrag[ht][1], a, 0, 0, 0);
      acc[ht] = a;
    }

    // Scan tile c-1 from LDS (pairwise b128 reads: 8 floats live).
    // Overlaps the MFMA latency above; barrier-free (single wave).
    if (c >= 1) {
      const float4* r0 = (const float4*)(cur + lane * CPAD);
      const float4* r1 = (const float4*)(cur + (lane + 64) * CPAD);
      const int tb = t0 + (c - 1) * 16;
#pragma unroll
      for (int i = 0; i < 4; ++i) {
        float4 v0 = r0[i];
        float4 v1 = r1[i];
#pragma unroll
        for (int k = 0; k < 4; ++k) {
          const int t = tb + i * 4 + k;
          const bool act = (t >= lo) && (t < hi);  // wave-uniform
          const float f0 = (k == 0) ? v0.x : (k == 1) ? v0.y : (k == 2) ? v0.z : v0.w;
          const float f1 = (k == 0) ? v1.x : (k == 1) ? v1.y : (k == 2) ? v1.z : v1.w;
          mem0 = fmaf(0.9f, mem0, f0);
          mem1 = fmaf(0.9f, mem1, f1);
          const bool s0 = (mem0 >= 1.0f);
          const bool s1 = (mem1 >= 1.0f);
          cnt0 += (act && s0) ? 1.0f : 0.0f;
          cnt1 += (act && s1) ? 1.0f : 0.0f;
          mem0 = s0 ? 0.0f : mem0;
          mem1 = s1 ? 0.0f : mem1;
        }
      }
    }

    // Write tile c: D[row=t=q*4+r][col=h=ht*16+ml] -> cur[h][t], r contiguous
    // => one ds_write_b128 per ht. In-order after the reads above.
#pragma unroll
    for (int ht = 0; ht < 8; ++ht) {
      float4 st = {acc[ht][0], acc[ht][1], acc[ht][2], acc[ht][3]};
      *(float4*)(cur + (ht * 16 + ml) * CPAD + q * 4) = st;
    }
  }

  // Final tile's scan.
  {
    const float4* r0 = (const float4*)(cur + lane * CPAD);
    const float4* r1 = (const float4*)(cur + (lane + 64) * CPAD);
    const int tb = t0 + (ntiles - 1) * 16;
#pragma unroll
    for (int i = 0; i < 4; ++i) {
      float4 v0 = r0[i];
      float4 v1 = r1[i];
#pragma unroll
      for (int k = 0; k < 4; ++k) {
        const int t = tb + i * 4 + k;
        const bool act = (t >= lo) && (t < hi);
        const float f0 = (k == 0) ? v0.x : (k == 1) ? v0.y : (k == 2) ? v0.z : v0.w;
        const float f1 = (k == 0) ? v1.x : (k == 1) ? v1.y : (k == 2) ? v1.z : v1.w;
        mem0 = fmaf(0.9f, mem0, f0);
        mem1 = fmaf(0.9f, mem1, f1);
        const bool s0 = (mem0 >= 1.0f);
        const bool s1 = (mem1 >= 1.0f);
        cnt0 += (act && s0) ? 1.0f : 0.0f;
        cnt1 += (act && s1) ? 1.0f : 0.0f;
        mem0 = s0 ? 0.0f : mem0;
        mem1 = s1 ? 0.0f : mem1;
      }
    }
  }

  float* pp = part + ((size_t)(seg * BB + b)) * HH;
  pp[lane] = cnt0;
  pp[lane + 64] = cnt1;
}

// ---------------------------------------------------------------------------
// Fused head: partial-count reduce + counts output + tda_net
// (150->64 relu ->64 relu) + fc1 (192->128). No atomics.
// ---------------------------------------------------------------------------
__global__ __launch_bounds__(HH) void fused_head(
    const float* __restrict__ part, const float* __restrict__ tda,
    const float* __restrict__ W1, const float* __restrict__ b1,
    const float* __restrict__ W2, const float* __restrict__ b2,
    const float* __restrict__ Wc1, const float* __restrict__ bc1,
    float* __restrict__ counts_out, float* __restrict__ hbuf)
{
  const int b = blockIdx.x, j = threadIdx.x;
  __shared__ float x[TDA_F];
  __shared__ float h1[64];
  __shared__ float f[HH + 64];

  float c = 0.0f;
#pragma unroll
  for (int s = 0; s < NSEG; ++s) c += part[((size_t)(s * BB + b)) * HH + j];
  counts_out[b * HH + j] = c;
  f[j] = c * (1.0f / TT);
  for (int i = j; i < TDA_F; i += HH) x[i] = tda[b * TDA_F + i];
  __syncthreads();
  if (j < 64) {
    float acc = b1[j];
    const float* wr = W1 + j * TDA_F;
#pragma unroll 5
    for (int i = 0; i < TDA_F; ++i) acc = fmaf(x[i], wr[i], acc);
    h1[j] = fmaxf(acc, 0.0f);
  }
  __syncthreads();
  if (j < 64) {
    float acc = b2[j];
    const float* wr = W2 + j * 64;
#pragma unroll
    for (int i = 0; i < 64; ++i) acc = fmaf(h1[i], wr[i], acc);
    f[HH + j] = fmaxf(acc, 0.0f);
  }
  __syncthreads();
  float acc = bc1[j];
  const float* wr = Wc1 + j * (HH + 64);
#pragma unroll 4
  for (int i = 0; i < HH + 64; ++i) acc = fmaf(f[i], wr[i], acc);
  hbuf[b * HH + j] = acc;
}

// ---------------------------------------------------------------------------
// BN (batch stats computed per-block from L2-resident hbuf) + relu +
// 128->4 GEMM.
// ---------------------------------------------------------------------------
__global__ __launch_bounds__(HH) void classifier2(
    const float* __restrict__ hbuf,
    const float* __restrict__ gamma, const float* __restrict__ beta,
    const float* __restrict__ Wc2, const float* __restrict__ bc2,
    float* __restrict__ out)
{
  const int b = blockIdx.x, j = threadIdx.x;
  float s0 = 0.f, q0 = 0.f, s1 = 0.f, q1 = 0.f;
  for (int r = 0; r < BB; r += 2) {
    float v0 = hbuf[r * HH + j];
    float v1 = hbuf[(r + 1) * HH + j];
    s0 += v0; q0 = fmaf(v0, v0, q0);
    s1 += v1; q1 = fmaf(v1, v1, q1);
  }
  const float mean = (s0 + s1) * (1.0f / BB);
  const float var = (q0 + q1) * (1.0f / BB) - mean * mean;
  const float rstd = rsqrtf(var + EPSV);

  float hn = (hbuf[b * HH + j] - mean) * rstd * gamma[j] + beta[j];
  hn = fmaxf(hn, 0.0f);

  __shared__ float red[NCLS][HH];
#pragma unroll
  for (int k = 0; k < NCLS; ++k) red[k][j] = hn * Wc2[k * HH + j];
  __syncthreads();
  for (int off = HH / 2; off >= 1; off >>= 1) {
    if (j < off) {
#pragma unroll
      for (int k = 0; k < NCLS; ++k) red[k][j] += red[k][j + off];
    }
    __syncthreads();
  }
  if (j < NCLS) out[b * NCLS + j] = red[j][0] + bc2[j];
}

// ---------------------------------------------------------------------------
extern "C" void kernel_launch(void* const* d_in, const int* in_sizes, int n_in,
                              void* d_out, int out_size, void* d_ws, size_t ws_size,
                              hipStream_t stream)
{
  const float* kin  = (const float*)d_in[0];   // [512,1000,64]
  const float* tda  = (const float*)d_in[1];   // [512,150]
  const float* Wfc  = (const float*)d_in[2];   // [128,64]
  const float* bfc  = (const float*)d_in[3];   // [128]
  const float* Wt1  = (const float*)d_in[4];   // [64,150]
  const float* bt1  = (const float*)d_in[5];   // [64]
  const float* Wt2  = (const float*)d_in[6];   // [64,64]
  const float* bt2  = (const float*)d_in[7];   // [64]
  const float* Wc1  = (const float*)d_in[8];   // [128,192]
  const float* bc1  = (const float*)d_in[9];   // [128]
  const float* gam  = (const float*)d_in[10];  // [128]
  const float* bet  = (const float*)d_in[11];  // [128]
  const float* Wc2  = (const float*)d_in[12];  // [4,128]
  const float* bc2  = (const float*)d_in[13];  // [4]

  float* out    = (float*)d_out;        // output 0: [512,4]
  float* counts = out + BB * NCLS;      // output 1: [512,128]

  float* part = (float*)d_ws;               // [8][512][128]  (2 MB)
  float* hbuf = part + NSEG * BB * HH;      // [512,128]

  snn_scan<<<BB * NSEG, 64, 0, stream>>>(kin, Wfc, bfc, part);
  fused_head<<<BB, HH, 0, stream>>>(part, tda, Wt1, bt1, Wt2, bt2,
                                    Wc1, bc1, counts, hbuf);
  classifier2<<<BB, HH, 0, stream>>>(hbuf, gam, bet, Wc2, bc2, out);
}